// Round 4
// baseline (55.816 us; speedup 1.0000x reference)
//
#include <hip/hip_runtime.h>
#include <math.h>

#define B_    16
#define N_    6
#define P_    70000
#define H_    112
#define W_    200
#define HW_   (H_ * W_)
#define BSN_  (B_ * N_)
#define HALF_ 56                      // rows per block (H_/2)
#define CELLS_ (HALF_ * W_)           // 11200 cells, 44.8 KB LDS
#define THREADS_ 1024

// ---------- shared math helpers (identical codegen everywhere) ----------

__device__ __forceinline__ float rdot(const float r[4], float x, float y, float z) {
    float s = r[0] * x;
    s = fmaf(r[1], y, s);
    s = fmaf(r[2], z, s);
    s = s + r[3];
    return s;
}

// scalar-register variant, same op order (bit-identical)
__device__ __forceinline__ float rdot4(float r0, float r1, float r2, float r3,
                                       float x, float y, float z) {
    float s = r0 * x;
    s = fmaf(r1, y, s);
    s = fmaf(r2, z, s);
    return s + r3;
}

// general 4x4 inverse via adjugate (matches jnp.linalg.inv bit-for-bit on
// the setup's view matrices — verified absmax 0.0 in rounds 1-3)
__device__ __forceinline__ void inv4(const float* m, float* o) {
    float inv[16];
    inv[0]  =  m[5]*m[10]*m[15] - m[5]*m[11]*m[14] - m[9]*m[6]*m[15] + m[9]*m[7]*m[14] + m[13]*m[6]*m[11] - m[13]*m[7]*m[10];
    inv[4]  = -m[4]*m[10]*m[15] + m[4]*m[11]*m[14] + m[8]*m[6]*m[15] - m[8]*m[7]*m[14] - m[12]*m[6]*m[11] + m[12]*m[7]*m[10];
    inv[8]  =  m[4]*m[9]*m[15]  - m[4]*m[11]*m[13] - m[8]*m[5]*m[15] + m[8]*m[7]*m[13] + m[12]*m[5]*m[11] - m[12]*m[7]*m[9];
    inv[12] = -m[4]*m[9]*m[14]  + m[4]*m[10]*m[13] + m[8]*m[5]*m[14] - m[8]*m[6]*m[13] - m[12]*m[5]*m[10] + m[12]*m[6]*m[9];
    inv[1]  = -m[1]*m[10]*m[15] + m[1]*m[11]*m[14] + m[9]*m[2]*m[15] - m[9]*m[3]*m[14] - m[13]*m[2]*m[11] + m[13]*m[3]*m[10];
    inv[5]  =  m[0]*m[10]*m[15] - m[0]*m[11]*m[14] - m[8]*m[2]*m[15] + m[8]*m[3]*m[14] + m[12]*m[2]*m[11] - m[12]*m[3]*m[10];
    inv[9]  = -m[0]*m[9]*m[15]  + m[0]*m[11]*m[13] + m[8]*m[1]*m[15] - m[8]*m[3]*m[13] - m[12]*m[1]*m[11] + m[12]*m[3]*m[9];
    inv[13] =  m[0]*m[9]*m[14]  - m[0]*m[10]*m[13] - m[8]*m[1]*m[14] + m[8]*m[2]*m[13] + m[12]*m[1]*m[10] - m[12]*m[2]*m[9];
    inv[2]  =  m[1]*m[6]*m[15]  - m[1]*m[7]*m[14]  - m[5]*m[2]*m[15] + m[5]*m[3]*m[14] + m[13]*m[2]*m[7]  - m[13]*m[3]*m[6];
    inv[6]  = -m[0]*m[6]*m[15]  + m[0]*m[7]*m[14]  + m[4]*m[2]*m[15] - m[4]*m[3]*m[14] - m[12]*m[2]*m[7]  + m[12]*m[3]*m[6];
    inv[10] =  m[0]*m[5]*m[15]  - m[0]*m[7]*m[13]  - m[4]*m[1]*m[15] + m[4]*m[3]*m[13] + m[12]*m[1]*m[7]  - m[12]*m[3]*m[5];
    inv[14] = -m[0]*m[5]*m[14]  + m[0]*m[6]*m[13]  + m[4]*m[1]*m[14] - m[4]*m[2]*m[13] - m[12]*m[1]*m[6]  + m[12]*m[2]*m[5];
    inv[3]  = -m[1]*m[6]*m[11]  + m[1]*m[7]*m[10]  + m[5]*m[2]*m[11] - m[5]*m[3]*m[10] - m[9]*m[2]*m[7]   + m[9]*m[3]*m[6];
    inv[7]  =  m[0]*m[6]*m[11]  - m[0]*m[7]*m[10]  - m[4]*m[2]*m[11] + m[4]*m[3]*m[10] + m[8]*m[2]*m[7]   - m[8]*m[3]*m[6];
    inv[11] = -m[0]*m[5]*m[11]  + m[0]*m[7]*m[9]   + m[4]*m[1]*m[11] - m[4]*m[3]*m[9]  - m[8]*m[1]*m[7]   + m[8]*m[3]*m[5];
    inv[15] =  m[0]*m[5]*m[10]  - m[0]*m[6]*m[9]   - m[4]*m[1]*m[10] + m[4]*m[2]*m[9]  + m[8]*m[1]*m[6]   - m[8]*m[2]*m[5];
    float det = m[0]*inv[0] + m[1]*inv[4] + m[2]*inv[8] + m[3]*inv[12];
    float rdet = 1.0f / det;
    for (int i = 0; i < 16; ++i) o[i] = inv[i] * rdet;
}

// Per-camera: Einv (rigid inverse) and PFC = scale_intrinsics4(K) @ Einv.
__device__ __forceinline__ void cam_mats(const float* Ein, const float* Kin,
                                         float E2[4], float PFC[3][4]) {
    float Einv[4][4];
    for (int i = 0; i < 3; ++i)
        for (int j = 0; j < 3; ++j)
            Einv[i][j] = Ein[j * 4 + i];          // R^T
    for (int i = 0; i < 3; ++i) {                  // -(R^T t), asc-j fma
        float s = Ein[0 * 4 + i] * Ein[0 * 4 + 3];
        s = fmaf(Ein[1 * 4 + i], Ein[1 * 4 + 3], s);
        s = fmaf(Ein[2 * 4 + i], Ein[2 * 4 + 3], s);
        Einv[i][3] = -s;
    }
    Einv[3][0] = Ein[12]; Einv[3][1] = Ein[13];
    Einv[3][2] = Ein[14]; Einv[3][3] = Ein[15];

    float K4[4][4] = {};
    K4[0][0] = Kin[0] * 0.25f;  K4[0][2] = Kin[2] * 0.25f;
    K4[1][1] = Kin[4] * 0.25f;  K4[1][2] = Kin[5] * 0.25f;
    K4[2][2] = 1.0f;            K4[3][3] = 1.0f;

    for (int i = 0; i < 3; ++i)
        for (int j = 0; j < 4; ++j) {
            float s = K4[i][0] * Einv[0][j];
            s = fmaf(K4[i][1], Einv[1][j], s);
            s = fmaf(K4[i][2], Einv[2][j], s);
            s = fmaf(K4[i][3], Einv[3][j], s);
            PFC[i][j] = s;
        }
    for (int j = 0; j < 4; ++j) E2[j] = Einv[2][j];
}

// ---------- K1: hoisted lidar->view transform (once per (b,p)) ----------

#define K1_THREADS 256
#define K1_SPLIT   64
#define K1_CHUNK   1094               // ceil(P_/K1_SPLIT)

__global__ __launch_bounds__(K1_THREADS) void k_pretransform(
        const float4* __restrict__ pc, const float* __restrict__ view,
        float4* __restrict__ tp) {
    __shared__ float sV[3][4];
    const int b = blockIdx.x;
    if (threadIdx.x == 0) {
        float Vi[16];
        inv4(&view[b * 16], Vi);
        for (int i = 0; i < 3; ++i)
            for (int j = 0; j < 4; ++j) sV[i][j] = Vi[i * 4 + j];
    }
    __syncthreads();
    const int start = blockIdx.y * K1_CHUNK;
    const int end   = min(start + K1_CHUNK, P_);
    const float4* pcb = pc + (size_t)b * P_;
    float4* tpb = tp + (size_t)b * P_;
    for (int p = start + threadIdx.x; p < end; p += K1_THREADS) {
        float4 pt = pcb[p];
        float lx = rdot(sV[0], pt.x, pt.y, pt.z);
        float ly = rdot(sV[1], pt.x, pt.y, pt.z);
        float lz = rdot(sV[2], pt.x, pt.y, pt.z);
        tpb[p] = make_float4(lx, ly, lz, pt.w);
    }
}

// ---------- K2: fused scatter+finalize, reading pre-transformed points ----

__global__ __launch_bounds__(THREADS_) void k_lidar_fused_ws(
        const float4* __restrict__ tp, const float* __restrict__ extr,
        const float* __restrict__ intr,
        float* __restrict__ out, const int* __restrict__ bev_side_p) {
    __shared__ int   win[CELLS_];      // 44.8 KB
    __shared__ float sE2[4];
    __shared__ float sP[3][4];

    // XCD-aware swizzle: co-locate all 12 blocks of one batch on one XCD
    // so the batch's 1.12 MB of transformed points stays L2-resident.
    const int i    = blockIdx.x;       // 0..191
    const int xcd  = i & 7;
    const int s    = i >> 3;           // 0..23
    const int b    = xcd + 8 * (s >= 12 ? 1 : 0);
    const int c12  = s % 12;
    const int m    = b * N_ + (c12 >> 1);
    const int rlo  = (c12 & 1) * HALF_;
    const int t    = threadIdx.x;

    if (t == 0) {
        float E2[4], PFC[3][4];
        cam_mats(&extr[m * 16], &intr[m * 9], E2, PFC);
        for (int j = 0; j < 4; ++j) sE2[j] = E2[j];
        for (int ii = 0; ii < 3; ++ii)
            for (int j = 0; j < 4; ++j) sP[ii][j] = PFC[ii][j];
    }
    for (int k = t; k < CELLS_; k += THREADS_) win[k] = -1;
    __syncthreads();

    // hoist projection rows to registers (no LDS reads in the point loop)
    const float P00 = sP[0][0], P01 = sP[0][1], P02 = sP[0][2], P03 = sP[0][3];
    const float P10 = sP[1][0], P11 = sP[1][1], P12 = sP[1][2], P13 = sP[1][3];
    const float P20 = sP[2][0], P21 = sP[2][1], P22 = sP[2][2], P23 = sP[2][3];

    // ---- Phase A: scatter (LDS atomicMax; corners in registers) ----
    const float4* tpb = tp + (size_t)b * P_;
    int c0 = -1, c1 = -1, c2 = -1, c3 = -1;   // max-p for grid corners
    for (int p = t; p < P_; p += THREADS_) {
        float4 pt = tpb[p];
        float px = rdot4(P00, P01, P02, P03, pt.x, pt.y, pt.z);
        float py = rdot4(P10, P11, P12, P13, pt.x, pt.y, pt.z);
        float pz = rdot4(P20, P21, P22, P23, pt.x, pt.y, pt.z);
        float denom = fmaxf(pz, 1e-6f);
        float x_ = px / denom;
        float y_ = py / denom;
        int ym = (int)fminf(fmaxf(y_, 0.0f), (float)(H_ - 1));
        int xm = (int)fminf(fmaxf(x_, 0.0f), (float)(W_ - 1));
        bool is_c = (xm == 0 || xm == W_ - 1) && (ym == 0 || ym == H_ - 1);
        int code = ((ym != 0) << 1) | (xm != 0);
        // p is strictly increasing per lane -> assign is max
        c0 = (is_c && code == 0) ? p : c0;
        c1 = (is_c && code == 1) ? p : c1;
        c2 = (is_c && code == 2) ? p : c2;
        c3 = (is_c && code == 3) ? p : c3;
        int rr = ym - rlo;
        if (!is_c && (unsigned)rr < (unsigned)HALF_)
            atomicMax(&win[rr * W_ + xm], p);
    }
    // wave-reduce corner maxima, then one atomic per wave per in-slab corner
    for (int d = 32; d; d >>= 1) {
        c0 = max(c0, __shfl_xor(c0, d));
        c1 = max(c1, __shfl_xor(c1, d));
        c2 = max(c2, __shfl_xor(c2, d));
        c3 = max(c3, __shfl_xor(c3, d));
    }
    if ((t & 63) == 0) {
        if (rlo == 0) {
            if (c0 >= 0) atomicMax(&win[0 * W_ + 0],        c0);
            if (c1 >= 0) atomicMax(&win[0 * W_ + (W_ - 1)], c1);
        } else {
            if (c2 >= 0) atomicMax(&win[(H_ - 1 - rlo) * W_ + 0],        c2);
            if (c3 >= 0) atomicMax(&win[(H_ - 1 - rlo) * W_ + (W_ - 1)], c3);
        }
    }
    __syncthreads();

    // ---- Phase B: finalize this block's rows ----
    const float bev_half = (float)bev_side_p[0] * 0.5f;   // 100.0
    const float clip_hi  = bev_half - 1.0f;               // 99.0
    const float E20 = sE2[0], E21 = sE2[1], E22 = sE2[2], E23 = sE2[3];
    const int base0 = (m * 2) * HW_ + rlo * W_;
    for (int r = t; r < CELLS_; r += THREADS_) {
        int w = win[r];
        float depth = 0.0f, iluv = 0.0f;
        if (w >= 0) {
            float4 pt = tpb[w];
            float z  = rdot4(E20, E21, E22, E23, pt.x, pt.y, pt.z);
            float px = rdot4(P00, P01, P02, P03, pt.x, pt.y, pt.z);
            float py = rdot4(P10, P11, P12, P13, pt.x, pt.y, pt.z);
            float pz = rdot4(P20, P21, P22, P23, pt.x, pt.y, pt.z);
            float denom = fmaxf(pz, 1e-6f);
            float x_ = px / denom;
            float y_ = py / denom;
            bool valid = (x_ > -0.5f) && (x_ < (float)W_ - 0.5f) &&
                         (y_ > -0.5f) && (y_ < (float)H_ - 0.5f) && (z > 0.0f);
            if (valid) {
                float d = fminf(fmaxf(pz, 0.0f), clip_hi);     // clip(normalizer,0,99)
                depth = d / bev_half;                           // /100
                float vi = fminf(fmaxf(pt.w, 0.0f), 255.0f);    // clip(ilu,0,255)
                iluv = log1pf(vi) / 5.545177444479562f;         // /log(256) as f32
            }
        }
        out[base0 + r]       = depth;
        out[base0 + HW_ + r] = iluv;
    }
}

// ---------- fallback (R3 path, used only if ws_size is too small) ----------

__global__ __launch_bounds__(THREADS_) void k_lidar_fused(
        const float4* __restrict__ pc, const float* __restrict__ extr,
        const float* __restrict__ intr, const float* __restrict__ view,
        float* __restrict__ out, const int* __restrict__ bev_side_p) {
    __shared__ int   win[CELLS_];
    __shared__ float sV[4][4];
    __shared__ float sE2[4];
    __shared__ float sP[3][4];

    const int i    = blockIdx.x;
    const int xcd  = i & 7;
    const int s    = i >> 3;
    const int b    = xcd + 8 * (s >= 12 ? 1 : 0);
    const int c12  = s % 12;
    const int m    = b * N_ + (c12 >> 1);
    const int rlo  = (c12 & 1) * HALF_;
    const int t    = threadIdx.x;

    if (t == 0) {
        float Vi[16];
        inv4(&view[b * 16], Vi);
        for (int ii = 0; ii < 4; ++ii)
            for (int j = 0; j < 4; ++j) sV[ii][j] = Vi[ii * 4 + j];
    } else if (t == 64) {
        float E2[4], PFC[3][4];
        cam_mats(&extr[m * 16], &intr[m * 9], E2, PFC);
        for (int j = 0; j < 4; ++j) sE2[j] = E2[j];
        for (int ii = 0; ii < 3; ++ii)
            for (int j = 0; j < 4; ++j) sP[ii][j] = PFC[ii][j];
    }
    for (int k = t; k < CELLS_; k += THREADS_) win[k] = -1;
    __syncthreads();

    const float4* pcb = pc + (size_t)b * P_;
    int c0 = -1, c1 = -1, c2 = -1, c3 = -1;
    for (int p = t; p < P_; p += THREADS_) {
        float4 pt = pcb[p];
        float lx = rdot(sV[0], pt.x, pt.y, pt.z);
        float ly = rdot(sV[1], pt.x, pt.y, pt.z);
        float lz = rdot(sV[2], pt.x, pt.y, pt.z);
        float px = rdot(sP[0], lx, ly, lz);
        float py = rdot(sP[1], lx, ly, lz);
        float pz = rdot(sP[2], lx, ly, lz);
        float denom = fmaxf(pz, 1e-6f);
        float x_ = px / denom;
        float y_ = py / denom;
        int ym = (int)fminf(fmaxf(y_, 0.0f), (float)(H_ - 1));
        int xm = (int)fminf(fmaxf(x_, 0.0f), (float)(W_ - 1));
        bool is_c = (xm == 0 || xm == W_ - 1) && (ym == 0 || ym == H_ - 1);
        int code = ((ym != 0) << 1) | (xm != 0);
        c0 = (is_c && code == 0) ? p : c0;
        c1 = (is_c && code == 1) ? p : c1;
        c2 = (is_c && code == 2) ? p : c2;
        c3 = (is_c && code == 3) ? p : c3;
        int rr = ym - rlo;
        if (!is_c && (unsigned)rr < (unsigned)HALF_)
            atomicMax(&win[rr * W_ + xm], p);
    }
    for (int d = 32; d; d >>= 1) {
        c0 = max(c0, __shfl_xor(c0, d));
        c1 = max(c1, __shfl_xor(c1, d));
        c2 = max(c2, __shfl_xor(c2, d));
        c3 = max(c3, __shfl_xor(c3, d));
    }
    if ((t & 63) == 0) {
        if (rlo == 0) {
            if (c0 >= 0) atomicMax(&win[0 * W_ + 0],        c0);
            if (c1 >= 0) atomicMax(&win[0 * W_ + (W_ - 1)], c1);
        } else {
            if (c2 >= 0) atomicMax(&win[(H_ - 1 - rlo) * W_ + 0],        c2);
            if (c3 >= 0) atomicMax(&win[(H_ - 1 - rlo) * W_ + (W_ - 1)], c3);
        }
    }
    __syncthreads();

    const float bev_half = (float)bev_side_p[0] * 0.5f;
    const float clip_hi  = bev_half - 1.0f;
    const int base0 = (m * 2) * HW_ + rlo * W_;
    for (int r = t; r < CELLS_; r += THREADS_) {
        int w = win[r];
        float depth = 0.0f, iluv = 0.0f;
        if (w >= 0) {
            float4 pt = pcb[w];
            float lx = rdot(sV[0], pt.x, pt.y, pt.z);
            float ly = rdot(sV[1], pt.x, pt.y, pt.z);
            float lz = rdot(sV[2], pt.x, pt.y, pt.z);
            float z  = rdot(sE2,   lx, ly, lz);
            float px = rdot(sP[0], lx, ly, lz);
            float py = rdot(sP[1], lx, ly, lz);
            float pz = rdot(sP[2], lx, ly, lz);
            float denom = fmaxf(pz, 1e-6f);
            float x_ = px / denom;
            float y_ = py / denom;
            bool valid = (x_ > -0.5f) && (x_ < (float)W_ - 0.5f) &&
                         (y_ > -0.5f) && (y_ < (float)H_ - 0.5f) && (z > 0.0f);
            if (valid) {
                float d = fminf(fmaxf(pz, 0.0f), clip_hi);
                depth = d / bev_half;
                float vi = fminf(fmaxf(pt.w, 0.0f), 255.0f);
                iluv = log1pf(vi) / 5.545177444479562f;
            }
        }
        out[base0 + r]       = depth;
        out[base0 + HW_ + r] = iluv;
    }
}

// ---------- launch ----------

extern "C" void kernel_launch(void* const* d_in, const int* in_sizes, int n_in,
                              void* d_out, int out_size, void* d_ws, size_t ws_size,
                              hipStream_t stream) {
    const float4* pc  = (const float4*)d_in[0];
    const float* extr = (const float*)d_in[1];
    const float* intr = (const float*)d_in[2];
    const float* view = (const float*)d_in[3];
    const int*   bev  = (const int*)d_in[4];
    float* out = (float*)d_out;

    const size_t need = (size_t)B_ * P_ * sizeof(float4);   // 17.92 MB
    if (ws_size >= need) {
        float4* tp = (float4*)d_ws;
        k_pretransform<<<dim3(B_, K1_SPLIT), dim3(K1_THREADS), 0, stream>>>(pc, view, tp);
        k_lidar_fused_ws<<<dim3(BSN_ * 2), dim3(THREADS_), 0, stream>>>(
            tp, extr, intr, out, bev);
    } else {
        k_lidar_fused<<<dim3(BSN_ * 2), dim3(THREADS_), 0, stream>>>(
            pc, extr, intr, view, out, bev);
    }
}

// Round 5
// 55.732 us; speedup vs baseline: 1.0015x; 1.0015x over previous
//
#include <hip/hip_runtime.h>
#include <math.h>

#define B_    16
#define N_    6
#define P_    70000
#define H_    112
#define W_    200
#define HW_   (H_ * W_)
#define BSN_  (B_ * N_)
#define QROWS  28                       // rows per scatter block (H_/4)
#define QCELLS (QROWS * W_)             // 5600 cells, 22.4 KB LDS
#define NQ     4
#define THREADS_ 1024

// ws float layout: [0,192) Vinv rows (16 b x 12) | [192,1344) PFC (96 m x 12)
// | [1344,1728) E2 (96 m x 4). u16 codes at byte offset 8192: 96 x 70000.
#define WS_VINV 0
#define WS_PFC  192
#define WS_E2   1344
#define WS_CODES_OFF 8192
#define WS_NEED (WS_CODES_OFF + (size_t)BSN_ * P_ * 2)

// corner cell codes ((ym<<8)|xm)
#define CC0 0u        // (0,0)
#define CC1 199u      // (0,199)
#define CC2 28416u    // (111,0)
#define CC3 28615u    // (111,199)

// ---------- shared math helpers (identical codegen everywhere) ----------

__device__ __forceinline__ float rdot(const float r[4], float x, float y, float z) {
    float s = r[0] * x;
    s = fmaf(r[1], y, s);
    s = fmaf(r[2], z, s);
    return s + r[3];
}

// scalar-register variant, same op order (bit-identical)
__device__ __forceinline__ float rdot4(float r0, float r1, float r2, float r3,
                                       float x, float y, float z) {
    float s = r0 * x;
    s = fmaf(r1, y, s);
    s = fmaf(r2, z, s);
    return s + r3;
}

// 4x4 inverse via adjugate (matches jnp.linalg.inv bit-for-bit here — absmax
// 0.0 through rounds 1-4)
__device__ __forceinline__ void inv4(const float* m, float* o) {
    float inv[16];
    inv[0]  =  m[5]*m[10]*m[15] - m[5]*m[11]*m[14] - m[9]*m[6]*m[15] + m[9]*m[7]*m[14] + m[13]*m[6]*m[11] - m[13]*m[7]*m[10];
    inv[4]  = -m[4]*m[10]*m[15] + m[4]*m[11]*m[14] + m[8]*m[6]*m[15] - m[8]*m[7]*m[14] - m[12]*m[6]*m[11] + m[12]*m[7]*m[10];
    inv[8]  =  m[4]*m[9]*m[15]  - m[4]*m[11]*m[13] - m[8]*m[5]*m[15] + m[8]*m[7]*m[13] + m[12]*m[5]*m[11] - m[12]*m[7]*m[9];
    inv[12] = -m[4]*m[9]*m[14]  + m[4]*m[10]*m[13] + m[8]*m[5]*m[14] - m[8]*m[6]*m[13] - m[12]*m[5]*m[10] + m[12]*m[6]*m[9];
    inv[1]  = -m[1]*m[10]*m[15] + m[1]*m[11]*m[14] + m[9]*m[2]*m[15] - m[9]*m[3]*m[14] - m[13]*m[2]*m[11] + m[13]*m[3]*m[10];
    inv[5]  =  m[0]*m[10]*m[15] - m[0]*m[11]*m[14] - m[8]*m[2]*m[15] + m[8]*m[3]*m[14] + m[12]*m[2]*m[11] - m[12]*m[3]*m[10];
    inv[9]  = -m[0]*m[9]*m[15]  + m[0]*m[11]*m[13] + m[8]*m[1]*m[15] - m[8]*m[3]*m[13] - m[12]*m[1]*m[11] + m[12]*m[3]*m[9];
    inv[13] =  m[0]*m[9]*m[14]  - m[0]*m[10]*m[13] - m[8]*m[1]*m[14] + m[8]*m[2]*m[13] + m[12]*m[1]*m[10] - m[12]*m[2]*m[9];
    inv[2]  =  m[1]*m[6]*m[15]  - m[1]*m[7]*m[14]  - m[5]*m[2]*m[15] + m[5]*m[3]*m[14] + m[13]*m[2]*m[7]  - m[13]*m[3]*m[6];
    inv[6]  = -m[0]*m[6]*m[15]  + m[0]*m[7]*m[14]  + m[4]*m[2]*m[15] - m[4]*m[3]*m[14] - m[12]*m[2]*m[7]  + m[12]*m[3]*m[6];
    inv[10] =  m[0]*m[5]*m[15]  - m[0]*m[7]*m[13]  - m[4]*m[1]*m[15] + m[4]*m[3]*m[13] + m[12]*m[1]*m[7]  - m[12]*m[3]*m[5];
    inv[14] = -m[0]*m[5]*m[14]  + m[0]*m[6]*m[13]  + m[4]*m[1]*m[14] - m[4]*m[2]*m[13] - m[12]*m[1]*m[6]  + m[12]*m[2]*m[5];
    inv[3]  = -m[1]*m[6]*m[11]  + m[1]*m[7]*m[10]  + m[5]*m[2]*m[11] - m[5]*m[3]*m[10] - m[9]*m[2]*m[7]   + m[9]*m[3]*m[6];
    inv[7]  =  m[0]*m[6]*m[11]  - m[0]*m[7]*m[10]  - m[4]*m[2]*m[11] + m[4]*m[3]*m[10] + m[8]*m[2]*m[7]   - m[8]*m[3]*m[6];
    inv[11] = -m[0]*m[5]*m[11]  + m[0]*m[7]*m[9]   + m[4]*m[1]*m[11] - m[4]*m[3]*m[9]  - m[8]*m[1]*m[7]   + m[8]*m[3]*m[5];
    inv[15] =  m[0]*m[5]*m[10]  - m[0]*m[6]*m[9]   - m[4]*m[1]*m[10] + m[4]*m[2]*m[9]  + m[8]*m[1]*m[6]   - m[8]*m[2]*m[5];
    float det = m[0]*inv[0] + m[1]*inv[4] + m[2]*inv[8] + m[3]*inv[12];
    float rdet = 1.0f / det;
    for (int i = 0; i < 16; ++i) o[i] = inv[i] * rdet;
}

// Per-camera: Einv (rigid inverse) and PFC = scale_intrinsics4(K) @ Einv.
__device__ __forceinline__ void cam_mats(const float* Ein, const float* Kin,
                                         float E2[4], float PFC[3][4]) {
    float Einv[4][4];
    for (int i = 0; i < 3; ++i)
        for (int j = 0; j < 3; ++j)
            Einv[i][j] = Ein[j * 4 + i];          // R^T
    for (int i = 0; i < 3; ++i) {                  // -(R^T t), asc-j fma
        float s = Ein[0 * 4 + i] * Ein[0 * 4 + 3];
        s = fmaf(Ein[1 * 4 + i], Ein[1 * 4 + 3], s);
        s = fmaf(Ein[2 * 4 + i], Ein[2 * 4 + 3], s);
        Einv[i][3] = -s;
    }
    Einv[3][0] = Ein[12]; Einv[3][1] = Ein[13];
    Einv[3][2] = Ein[14]; Einv[3][3] = Ein[15];

    float K4[4][4] = {};
    K4[0][0] = Kin[0] * 0.25f;  K4[0][2] = Kin[2] * 0.25f;
    K4[1][1] = Kin[4] * 0.25f;  K4[1][2] = Kin[5] * 0.25f;
    K4[2][2] = 1.0f;            K4[3][3] = 1.0f;

    for (int i = 0; i < 3; ++i)
        for (int j = 0; j < 4; ++j) {
            float s = K4[i][0] * Einv[0][j];
            s = fmaf(K4[i][1], Einv[1][j], s);
            s = fmaf(K4[i][2], Einv[2][j], s);
            s = fmaf(K4[i][3], Einv[3][j], s);
            PFC[i][j] = s;
        }
    for (int j = 0; j < 4; ++j) E2[j] = Einv[2][j];
}

// ---------- K0: all matrices once -> ws ----------

__global__ __launch_bounds__(128) void k_mats(
        const float* __restrict__ extr, const float* __restrict__ intr,
        const float* __restrict__ view, float* __restrict__ wsf) {
    const int t = threadIdx.x;
    if (t < BSN_) {
        float E2[4], PFC[3][4];
        cam_mats(&extr[t * 16], &intr[t * 9], E2, PFC);
        for (int i = 0; i < 3; ++i)
            for (int j = 0; j < 4; ++j) wsf[WS_PFC + t * 12 + i * 4 + j] = PFC[i][j];
        for (int j = 0; j < 4; ++j) wsf[WS_E2 + t * 4 + j] = E2[j];
    } else if (t < BSN_ + B_) {
        int b = t - BSN_;
        float Vi[16];
        inv4(&view[b * 16], Vi);
        for (int k = 0; k < 12; ++k) wsf[WS_VINV + b * 12 + k] = Vi[k];  // rows 0..2
    }
}

// ---------- K1: per (b,p): project into all 6 cameras, write u16 cell codes

#define K1T 256

__global__ __launch_bounds__(K1T) void k_codes(
        const float4* __restrict__ pc, const float* __restrict__ wsf,
        unsigned short* __restrict__ codes) {
    __shared__ float sM[84];           // 12 Vinv + 6*12 PFC
    const int b = blockIdx.x;
    const int t = threadIdx.x;
    if (t < 12)       sM[t] = wsf[WS_VINV + b * 12 + t];
    else if (t < 84)  sM[t] = wsf[WS_PFC + b * 6 * 12 + (t - 12)];
    __syncthreads();

    float V[12], Pm[6][12];
    #pragma unroll
    for (int k = 0; k < 12; ++k) V[k] = sM[k];
    #pragma unroll
    for (int n = 0; n < 6; ++n)
        #pragma unroll
        for (int k = 0; k < 12; ++k) Pm[n][k] = sM[12 + n * 12 + k];

    const int p = blockIdx.y * K1T + t;
    if (p >= P_) return;
    float4 pt = pc[(size_t)b * P_ + p];
    float lx = rdot4(V[0], V[1], V[2],  V[3],  pt.x, pt.y, pt.z);
    float ly = rdot4(V[4], V[5], V[6],  V[7],  pt.x, pt.y, pt.z);
    float lz = rdot4(V[8], V[9], V[10], V[11], pt.x, pt.y, pt.z);
    #pragma unroll
    for (int n = 0; n < 6; ++n) {
        float px = rdot4(Pm[n][0], Pm[n][1], Pm[n][2],  Pm[n][3],  lx, ly, lz);
        float py = rdot4(Pm[n][4], Pm[n][5], Pm[n][6],  Pm[n][7],  lx, ly, lz);
        float pz = rdot4(Pm[n][8], Pm[n][9], Pm[n][10], Pm[n][11], lx, ly, lz);
        float denom = fmaxf(pz, 1e-6f);
        float x_ = px / denom;
        float y_ = py / denom;
        int ym = (int)fminf(fmaxf(y_, 0.0f), (float)(H_ - 1));
        int xm = (int)fminf(fmaxf(x_, 0.0f), (float)(W_ - 1));
        codes[(size_t)(b * N_ + n) * P_ + p] = (unsigned short)((ym << 8) | xm);
    }
}

// ---------- K2: fused scatter (via codes) + finalize. Block = (camera, quarter)

__global__ __launch_bounds__(THREADS_) void k_scatfin(
        const float4* __restrict__ pc, const unsigned short* __restrict__ codes,
        const float* __restrict__ wsf, float* __restrict__ out,
        const int* __restrict__ bev_side_p) {
    __shared__ int   win[QCELLS];      // 22.4 KB
    __shared__ float sM[28];           // 0..11 Vinv, 12..23 PFC, 24..27 E2

    // XCD swizzle: 384 blocks, 48 per XCD = 2 batches' worth (24 blocks/batch)
    const int i   = blockIdx.x;
    const int xcd = i & 7;
    const int j   = i >> 3;            // 0..47
    const int b   = xcd + 8 * (j >= 24 ? 1 : 0);
    const int r   = j % 24;
    const int cam = r >> 2;
    const int q   = r & 3;
    const int m   = b * N_ + cam;
    const int rlo = q * QROWS;
    const int t   = threadIdx.x;

    for (int k = t; k < QCELLS; k += THREADS_) win[k] = -1;
    if (t < 12)       sM[t] = wsf[WS_VINV + b * 12 + t];
    else if (t < 24)  sM[t] = wsf[WS_PFC + m * 12 + (t - 12)];
    else if (t < 28)  sM[t] = wsf[WS_E2 + m * 4 + (t - 24)];
    __syncthreads();

    // ---- Phase A: scatter codes (LDS atomicMax; corners in registers) ----
    const unsigned short* cm = codes + (size_t)m * P_;
    int c0 = -1, c1 = -1, c2 = -1, c3 = -1;
    for (int p = t; p < P_; p += THREADS_) {
        unsigned int c = cm[p];
        bool i0 = (c == CC0), i1 = (c == CC1), i2 = (c == CC2), i3 = (c == CC3);
        // p strictly increasing per lane -> assign is max
        c0 = i0 ? p : c0;  c1 = i1 ? p : c1;
        c2 = i2 ? p : c2;  c3 = i3 ? p : c3;
        int ym = (int)(c >> 8), xm = (int)(c & 255u);
        int rr = ym - rlo;
        if (!(i0 | i1 | i2 | i3) && (unsigned)rr < (unsigned)QROWS)
            atomicMax(&win[rr * W_ + xm], p);
    }
    for (int d = 32; d; d >>= 1) {
        c0 = max(c0, __shfl_xor(c0, d));
        c1 = max(c1, __shfl_xor(c1, d));
        c2 = max(c2, __shfl_xor(c2, d));
        c3 = max(c3, __shfl_xor(c3, d));
    }
    if ((t & 63) == 0) {
        if (q == 0) {                                   // rows 0..27: (0,0),(0,199)
            if (c0 >= 0) atomicMax(&win[0],   c0);
            if (c1 >= 0) atomicMax(&win[199], c1);
        } else if (q == 3) {                            // rows 84..111: (111,0),(111,199)
            if (c2 >= 0) atomicMax(&win[(H_ - 1 - rlo) * W_ + 0],   c2);
            if (c3 >= 0) atomicMax(&win[(H_ - 1 - rlo) * W_ + 199], c3);
        }
    }
    __syncthreads();

    // ---- Phase B: finalize this block's rows (recompute winners only) ----
    const float bev_half = (float)bev_side_p[0] * 0.5f;   // 100.0
    const float clip_hi  = bev_half - 1.0f;               // 99.0
    const float4* pcb = pc + (size_t)b * P_;
    const int base0 = (m * 2) * HW_ + rlo * W_;
    for (int rr = t; rr < QCELLS; rr += THREADS_) {
        int w = win[rr];
        float depth = 0.0f, iluv = 0.0f;
        if (w >= 0) {
            float4 pt = pcb[w];
            float lx = rdot4(sM[0],  sM[1],  sM[2],  sM[3],  pt.x, pt.y, pt.z);
            float ly = rdot4(sM[4],  sM[5],  sM[6],  sM[7],  pt.x, pt.y, pt.z);
            float lz = rdot4(sM[8],  sM[9],  sM[10], sM[11], pt.x, pt.y, pt.z);
            float z  = rdot4(sM[24], sM[25], sM[26], sM[27], lx, ly, lz);
            float px = rdot4(sM[12], sM[13], sM[14], sM[15], lx, ly, lz);
            float py = rdot4(sM[16], sM[17], sM[18], sM[19], lx, ly, lz);
            float pz = rdot4(sM[20], sM[21], sM[22], sM[23], lx, ly, lz);
            float denom = fmaxf(pz, 1e-6f);
            float x_ = px / denom;
            float y_ = py / denom;
            bool valid = (x_ > -0.5f) && (x_ < (float)W_ - 0.5f) &&
                         (y_ > -0.5f) && (y_ < (float)H_ - 0.5f) && (z > 0.0f);
            if (valid) {
                float d = fminf(fmaxf(pz, 0.0f), clip_hi);     // clip(normalizer,0,99)
                depth = d / bev_half;                           // /100
                float vi = fminf(fmaxf(pt.w, 0.0f), 255.0f);    // clip(ilu,0,255)
                iluv = log1pf(vi) / 5.545177444479562f;         // /log(256) as f32
            }
        }
        out[base0 + rr]       = depth;
        out[base0 + HW_ + rr] = iluv;
    }
}

// ---------- fallback (R3 single-kernel path, if ws too small) ----------

#define HALF_ 56
#define CELLS_ (HALF_ * W_)

__global__ __launch_bounds__(THREADS_) void k_lidar_fused(
        const float4* __restrict__ pc, const float* __restrict__ extr,
        const float* __restrict__ intr, const float* __restrict__ view,
        float* __restrict__ out, const int* __restrict__ bev_side_p) {
    __shared__ int   win[CELLS_];
    __shared__ float sV[4][4];
    __shared__ float sE2[4];
    __shared__ float sP[3][4];

    const int i    = blockIdx.x;
    const int xcd  = i & 7;
    const int s    = i >> 3;
    const int b    = xcd + 8 * (s >= 12 ? 1 : 0);
    const int c12  = s % 12;
    const int m    = b * N_ + (c12 >> 1);
    const int rlo  = (c12 & 1) * HALF_;
    const int t    = threadIdx.x;

    if (t == 0) {
        float Vi[16];
        inv4(&view[b * 16], Vi);
        for (int ii = 0; ii < 4; ++ii)
            for (int jj = 0; jj < 4; ++jj) sV[ii][jj] = Vi[ii * 4 + jj];
    } else if (t == 64) {
        float E2[4], PFC[3][4];
        cam_mats(&extr[m * 16], &intr[m * 9], E2, PFC);
        for (int jj = 0; jj < 4; ++jj) sE2[jj] = E2[jj];
        for (int ii = 0; ii < 3; ++ii)
            for (int jj = 0; jj < 4; ++jj) sP[ii][jj] = PFC[ii][jj];
    }
    for (int k = t; k < CELLS_; k += THREADS_) win[k] = -1;
    __syncthreads();

    const float4* pcb = pc + (size_t)b * P_;
    int c0 = -1, c1 = -1, c2 = -1, c3 = -1;
    for (int p = t; p < P_; p += THREADS_) {
        float4 pt = pcb[p];
        float lx = rdot(sV[0], pt.x, pt.y, pt.z);
        float ly = rdot(sV[1], pt.x, pt.y, pt.z);
        float lz = rdot(sV[2], pt.x, pt.y, pt.z);
        float px = rdot(sP[0], lx, ly, lz);
        float py = rdot(sP[1], lx, ly, lz);
        float pz = rdot(sP[2], lx, ly, lz);
        float denom = fmaxf(pz, 1e-6f);
        float x_ = px / denom;
        float y_ = py / denom;
        int ym = (int)fminf(fmaxf(y_, 0.0f), (float)(H_ - 1));
        int xm = (int)fminf(fmaxf(x_, 0.0f), (float)(W_ - 1));
        bool is_c = (xm == 0 || xm == W_ - 1) && (ym == 0 || ym == H_ - 1);
        int code = ((ym != 0) << 1) | (xm != 0);
        c0 = (is_c && code == 0) ? p : c0;
        c1 = (is_c && code == 1) ? p : c1;
        c2 = (is_c && code == 2) ? p : c2;
        c3 = (is_c && code == 3) ? p : c3;
        int rr = ym - rlo;
        if (!is_c && (unsigned)rr < (unsigned)HALF_)
            atomicMax(&win[rr * W_ + xm], p);
    }
    for (int d = 32; d; d >>= 1) {
        c0 = max(c0, __shfl_xor(c0, d));
        c1 = max(c1, __shfl_xor(c1, d));
        c2 = max(c2, __shfl_xor(c2, d));
        c3 = max(c3, __shfl_xor(c3, d));
    }
    if ((t & 63) == 0) {
        if (rlo == 0) {
            if (c0 >= 0) atomicMax(&win[0],   c0);
            if (c1 >= 0) atomicMax(&win[199], c1);
        } else {
            if (c2 >= 0) atomicMax(&win[(H_ - 1 - rlo) * W_ + 0],   c2);
            if (c3 >= 0) atomicMax(&win[(H_ - 1 - rlo) * W_ + 199], c3);
        }
    }
    __syncthreads();

    const float bev_half = (float)bev_side_p[0] * 0.5f;
    const float clip_hi  = bev_half - 1.0f;
    const int base0 = (m * 2) * HW_ + rlo * W_;
    for (int rr = t; rr < CELLS_; rr += THREADS_) {
        int w = win[rr];
        float depth = 0.0f, iluv = 0.0f;
        if (w >= 0) {
            float4 pt = pcb[w];
            float lx = rdot(sV[0], pt.x, pt.y, pt.z);
            float ly = rdot(sV[1], pt.x, pt.y, pt.z);
            float lz = rdot(sV[2], pt.x, pt.y, pt.z);
            float z  = rdot(sE2,   lx, ly, lz);
            float px = rdot(sP[0], lx, ly, lz);
            float py = rdot(sP[1], lx, ly, lz);
            float pz = rdot(sP[2], lx, ly, lz);
            float denom = fmaxf(pz, 1e-6f);
            float x_ = px / denom;
            float y_ = py / denom;
            bool valid = (x_ > -0.5f) && (x_ < (float)W_ - 0.5f) &&
                         (y_ > -0.5f) && (y_ < (float)H_ - 0.5f) && (z > 0.0f);
            if (valid) {
                float d = fminf(fmaxf(pz, 0.0f), clip_hi);
                depth = d / bev_half;
                float vi = fminf(fmaxf(pt.w, 0.0f), 255.0f);
                iluv = log1pf(vi) / 5.545177444479562f;
            }
        }
        out[base0 + rr]       = depth;
        out[base0 + HW_ + rr] = iluv;
    }
}

// ---------- launch ----------

extern "C" void kernel_launch(void* const* d_in, const int* in_sizes, int n_in,
                              void* d_out, int out_size, void* d_ws, size_t ws_size,
                              hipStream_t stream) {
    const float4* pc  = (const float4*)d_in[0];
    const float* extr = (const float*)d_in[1];
    const float* intr = (const float*)d_in[2];
    const float* view = (const float*)d_in[3];
    const int*   bev  = (const int*)d_in[4];
    float* out = (float*)d_out;

    if (ws_size >= WS_NEED) {
        float* wsf = (float*)d_ws;
        unsigned short* codes = (unsigned short*)((char*)d_ws + WS_CODES_OFF);
        k_mats<<<dim3(1), dim3(128), 0, stream>>>(extr, intr, view, wsf);
        k_codes<<<dim3(B_, (P_ + K1T - 1) / K1T), dim3(K1T), 0, stream>>>(pc, wsf, codes);
        k_scatfin<<<dim3(BSN_ * NQ), dim3(THREADS_), 0, stream>>>(pc, codes, wsf, out, bev);
    } else {
        k_lidar_fused<<<dim3(BSN_ * 2), dim3(THREADS_), 0, stream>>>(
            pc, extr, intr, view, out, bev);
    }
}

// Round 6
// 48.150 us; speedup vs baseline: 1.1592x; 1.1575x over previous
//
#include <hip/hip_runtime.h>
#include <math.h>

#define B_    16
#define N_    6
#define P_    70000
#define H_    112
#define W_    200
#define HW_   (H_ * W_)
#define BSN_  (B_ * N_)
#define QROWS  28                       // rows per scatter block (H_/4)
#define QCELLS (QROWS * W_)             // 5600 cells, 22.4 KB LDS
#define THREADS_ 1024

// ws: u16 cell codes, camera-major: [96][70000]. 13.44 MB.
#define WS_NEED ((size_t)BSN_ * P_ * 2)
#define PVEC (P_ / 8)                   // 8750 uint4 per camera plane (exact)

// corner cell codes ((ym<<8)|xm)
#define CC0 0u        // (0,0)
#define CC1 199u      // (0,199)
#define CC2 28416u    // (111,0)
#define CC3 28615u    // (111,199)

// ---------- shared math helpers (identical codegen everywhere) ----------

__device__ __forceinline__ float rdot(const float r[4], float x, float y, float z) {
    float s = r[0] * x;
    s = fmaf(r[1], y, s);
    s = fmaf(r[2], z, s);
    return s + r[3];
}

__device__ __forceinline__ float rdot4(float r0, float r1, float r2, float r3,
                                       float x, float y, float z) {
    float s = r0 * x;
    s = fmaf(r1, y, s);
    s = fmaf(r2, z, s);
    return s + r3;
}

// 4x4 inverse via adjugate (matches jnp.linalg.inv bit-for-bit here — absmax
// 0.0 through rounds 1-5)
__device__ __forceinline__ void inv4(const float* m, float* o) {
    float inv[16];
    inv[0]  =  m[5]*m[10]*m[15] - m[5]*m[11]*m[14] - m[9]*m[6]*m[15] + m[9]*m[7]*m[14] + m[13]*m[6]*m[11] - m[13]*m[7]*m[10];
    inv[4]  = -m[4]*m[10]*m[15] + m[4]*m[11]*m[14] + m[8]*m[6]*m[15] - m[8]*m[7]*m[14] - m[12]*m[6]*m[11] + m[12]*m[7]*m[10];
    inv[8]  =  m[4]*m[9]*m[15]  - m[4]*m[11]*m[13] - m[8]*m[5]*m[15] + m[8]*m[7]*m[13] + m[12]*m[5]*m[11] - m[12]*m[7]*m[9];
    inv[12] = -m[4]*m[9]*m[14]  + m[4]*m[10]*m[13] + m[8]*m[5]*m[14] - m[8]*m[6]*m[13] - m[12]*m[5]*m[10] + m[12]*m[6]*m[9];
    inv[1]  = -m[1]*m[10]*m[15] + m[1]*m[11]*m[14] + m[9]*m[2]*m[15] - m[9]*m[3]*m[14] - m[13]*m[2]*m[11] + m[13]*m[3]*m[10];
    inv[5]  =  m[0]*m[10]*m[15] - m[0]*m[11]*m[14] - m[8]*m[2]*m[15] + m[8]*m[3]*m[14] + m[12]*m[2]*m[11] - m[12]*m[3]*m[10];
    inv[9]  = -m[0]*m[9]*m[15]  + m[0]*m[11]*m[13] + m[8]*m[1]*m[15] - m[8]*m[3]*m[13] - m[12]*m[1]*m[11] + m[12]*m[3]*m[9];
    inv[13] =  m[0]*m[9]*m[14]  - m[0]*m[10]*m[13] - m[8]*m[1]*m[14] + m[8]*m[2]*m[13] + m[12]*m[1]*m[10] - m[12]*m[2]*m[9];
    inv[2]  =  m[1]*m[6]*m[15]  - m[1]*m[7]*m[14]  - m[5]*m[2]*m[15] + m[5]*m[3]*m[14] + m[13]*m[2]*m[7]  - m[13]*m[3]*m[6];
    inv[6]  = -m[0]*m[6]*m[15]  + m[0]*m[7]*m[14]  + m[4]*m[2]*m[15] - m[4]*m[3]*m[14] - m[12]*m[2]*m[7]  + m[12]*m[3]*m[6];
    inv[10] =  m[0]*m[5]*m[15]  - m[0]*m[7]*m[13]  - m[4]*m[1]*m[15] + m[4]*m[3]*m[13] + m[12]*m[1]*m[7]  - m[12]*m[3]*m[5];
    inv[14] = -m[0]*m[5]*m[14]  + m[0]*m[6]*m[13]  + m[4]*m[1]*m[14] - m[4]*m[2]*m[13] - m[12]*m[1]*m[6]  + m[12]*m[2]*m[5];
    inv[3]  = -m[1]*m[6]*m[11]  + m[1]*m[7]*m[10]  + m[5]*m[2]*m[11] - m[5]*m[3]*m[10] - m[9]*m[2]*m[7]   + m[9]*m[3]*m[6];
    inv[7]  =  m[0]*m[6]*m[11]  - m[0]*m[7]*m[10]  - m[4]*m[2]*m[11] + m[4]*m[3]*m[10] + m[8]*m[2]*m[7]   - m[8]*m[3]*m[6];
    inv[11] = -m[0]*m[5]*m[11]  + m[0]*m[7]*m[9]   + m[4]*m[1]*m[11] - m[4]*m[3]*m[9]  - m[8]*m[1]*m[7]   + m[8]*m[3]*m[5];
    inv[15] =  m[0]*m[5]*m[10]  - m[0]*m[6]*m[9]   - m[4]*m[1]*m[10] + m[4]*m[2]*m[9]  + m[8]*m[1]*m[6]   - m[8]*m[2]*m[5];
    float det = m[0]*inv[0] + m[1]*inv[4] + m[2]*inv[8] + m[3]*inv[12];
    float rdet = 1.0f / det;
    for (int i = 0; i < 16; ++i) o[i] = inv[i] * rdet;
}

// Per-camera: Einv (rigid inverse) and PFC = scale_intrinsics4(K) @ Einv.
__device__ __forceinline__ void cam_mats(const float* Ein, const float* Kin,
                                         float E2[4], float PFC[3][4]) {
    float Einv[4][4];
    for (int i = 0; i < 3; ++i)
        for (int j = 0; j < 3; ++j)
            Einv[i][j] = Ein[j * 4 + i];          // R^T
    for (int i = 0; i < 3; ++i) {                  // -(R^T t), asc-j fma
        float s = Ein[0 * 4 + i] * Ein[0 * 4 + 3];
        s = fmaf(Ein[1 * 4 + i], Ein[1 * 4 + 3], s);
        s = fmaf(Ein[2 * 4 + i], Ein[2 * 4 + 3], s);
        Einv[i][3] = -s;
    }
    Einv[3][0] = Ein[12]; Einv[3][1] = Ein[13];
    Einv[3][2] = Ein[14]; Einv[3][3] = Ein[15];

    float K4[4][4] = {};
    K4[0][0] = Kin[0] * 0.25f;  K4[0][2] = Kin[2] * 0.25f;
    K4[1][1] = Kin[4] * 0.25f;  K4[1][2] = Kin[5] * 0.25f;
    K4[2][2] = 1.0f;            K4[3][3] = 1.0f;

    for (int i = 0; i < 3; ++i)
        for (int j = 0; j < 4; ++j) {
            float s = K4[i][0] * Einv[0][j];
            s = fmaf(K4[i][1], Einv[1][j], s);
            s = fmaf(K4[i][2], Einv[2][j], s);
            s = fmaf(K4[i][3], Einv[3][j], s);
            PFC[i][j] = s;
        }
    for (int j = 0; j < 4; ++j) E2[j] = Einv[2][j];
}

// ---------- K1: per (b,p): project into all 6 cameras, write u16 cell codes

#define K1T 256

__global__ __launch_bounds__(K1T) void k_codes(
        const float4* __restrict__ pc, const float* __restrict__ extr,
        const float* __restrict__ intr, const float* __restrict__ view,
        unsigned short* __restrict__ codes) {
    __shared__ float sM[84];           // 0..11 Vinv rows, 12.. 6x12 PFC
    const int b = blockIdx.x;
    const int t = threadIdx.x;
    if (t == 0) {                       // wave 0: Vinv
        float Vi[16];
        inv4(&view[b * 16], Vi);
        for (int k = 0; k < 12; ++k) sM[k] = Vi[k];
    } else if (t >= 64 && t < 64 + N_) {  // wave 1: 6 cameras
        int n = t - 64;
        float E2[4], PFC[3][4];
        cam_mats(&extr[(b * N_ + n) * 16], &intr[(b * N_ + n) * 9], E2, PFC);
        for (int i = 0; i < 3; ++i)
            for (int j = 0; j < 4; ++j) sM[12 + n * 12 + i * 4 + j] = PFC[i][j];
    }
    __syncthreads();

    const int p = blockIdx.y * K1T + t;
    if (p >= P_) return;
    float4 pt = pc[(size_t)b * P_ + p];
    float lx = rdot(&sM[0], pt.x, pt.y, pt.z);
    float ly = rdot(&sM[4], pt.x, pt.y, pt.z);
    float lz = rdot(&sM[8], pt.x, pt.y, pt.z);
    #pragma unroll
    for (int n = 0; n < 6; ++n) {
        const float* Pm = &sM[12 + n * 12];
        float px = rdot(&Pm[0], lx, ly, lz);
        float py = rdot(&Pm[4], lx, ly, lz);
        float pz = rdot(&Pm[8], lx, ly, lz);
        float denom = fmaxf(pz, 1e-6f);
        float x_ = px / denom;
        float y_ = py / denom;
        int ym = (int)fminf(fmaxf(y_, 0.0f), (float)(H_ - 1));
        int xm = (int)fminf(fmaxf(x_, 0.0f), (float)(W_ - 1));
        codes[(size_t)(b * N_ + n) * P_ + p] = (unsigned short)((ym << 8) | xm);
    }
}

// ---------- K2: fused scatter (vectorized code scan) + finalize ----------
// Block = (camera, quarter). Codes read as uint4 (8 points/thread/iter) to
// cut the dependent-load chain 68 -> 9.

__global__ __launch_bounds__(THREADS_) void k_scatfin(
        const float4* __restrict__ pc, const unsigned short* __restrict__ codes,
        const float* __restrict__ extr, const float* __restrict__ intr,
        const float* __restrict__ view,
        float* __restrict__ out, const int* __restrict__ bev_side_p) {
    __shared__ int   win[QCELLS];      // 22.4 KB
    __shared__ float sM[28];           // 0..11 Vinv, 12..23 PFC, 24..27 E2

    // XCD swizzle: 384 blocks, 48 per XCD = 2 batches (24 blocks/batch);
    // matches k_codes' placement (its blockIdx.x=b -> XCD b%8), so the
    // camera's 140 KB code plane is read from the writer XCD's L2.
    const int i   = blockIdx.x;
    const int xcd = i & 7;
    const int j   = i >> 3;            // 0..47
    const int b   = xcd + 8 * (j >= 24 ? 1 : 0);
    const int r   = j % 24;
    const int cam = r >> 2;
    const int q   = r & 3;
    const int m   = b * N_ + cam;
    const int rlo = q * QROWS;
    const int t   = threadIdx.x;

    if (t == 0) {                       // wave 0: Vinv
        float Vi[16];
        inv4(&view[b * 16], Vi);
        for (int k = 0; k < 12; ++k) sM[k] = Vi[k];
    } else if (t == 64) {               // wave 1: this camera
        float E2[4], PFC[3][4];
        cam_mats(&extr[m * 16], &intr[m * 9], E2, PFC);
        for (int ii = 0; ii < 3; ++ii)
            for (int jj = 0; jj < 4; ++jj) sM[12 + ii * 4 + jj] = PFC[ii][jj];
        for (int jj = 0; jj < 4; ++jj) sM[24 + jj] = E2[jj];
    }
    for (int k = t; k < QCELLS; k += THREADS_) win[k] = -1;
    __syncthreads();

    // ---- Phase A: vectorized code scan (8 codes per uint4) ----
    const uint4* cm4 = (const uint4*)(codes + (size_t)m * P_);
    int c0 = -1, c1 = -1, c2 = -1, c3 = -1;
    for (int v = t; v < PVEC; v += THREADS_) {
        uint4 w4 = cm4[v];
        int pbase = v * 8;
        unsigned int cs[4] = {w4.x, w4.y, w4.z, w4.w};
        #pragma unroll
        for (int h = 0; h < 4; ++h) {
            #pragma unroll
            for (int lohi = 0; lohi < 2; ++lohi) {
                unsigned int c = lohi ? (cs[h] >> 16) : (cs[h] & 0xffffu);
                int p = pbase + h * 2 + lohi;       // ascending within thread
                bool i0 = (c == CC0), i1 = (c == CC1),
                     i2 = (c == CC2), i3 = (c == CC3);
                c0 = i0 ? p : c0;  c1 = i1 ? p : c1;
                c2 = i2 ? p : c2;  c3 = i3 ? p : c3;
                int rr = (int)(c >> 8) - rlo;
                if (!(i0 | i1 | i2 | i3) && (unsigned)rr < (unsigned)QROWS)
                    atomicMax(&win[rr * W_ + (int)(c & 255u)], p);
            }
        }
    }
    for (int d = 32; d; d >>= 1) {
        c0 = max(c0, __shfl_xor(c0, d));
        c1 = max(c1, __shfl_xor(c1, d));
        c2 = max(c2, __shfl_xor(c2, d));
        c3 = max(c3, __shfl_xor(c3, d));
    }
    if ((t & 63) == 0) {
        if (q == 0) {                                   // rows 0..27: (0,0),(0,199)
            if (c0 >= 0) atomicMax(&win[0],   c0);
            if (c1 >= 0) atomicMax(&win[199], c1);
        } else if (q == 3) {                            // rows 84..111
            if (c2 >= 0) atomicMax(&win[(H_ - 1 - rlo) * W_ + 0],   c2);
            if (c3 >= 0) atomicMax(&win[(H_ - 1 - rlo) * W_ + 199], c3);
        }
    }
    __syncthreads();

    // ---- Phase B: finalize this block's rows (recompute winners only) ----
    const float bev_half = (float)bev_side_p[0] * 0.5f;   // 100.0
    const float clip_hi  = bev_half - 1.0f;               // 99.0
    const float4* pcb = pc + (size_t)b * P_;
    const int base0 = (m * 2) * HW_ + rlo * W_;
    for (int rr = t; rr < QCELLS; rr += THREADS_) {
        int w = win[rr];
        float depth = 0.0f, iluv = 0.0f;
        if (w >= 0) {
            float4 pt = pcb[w];
            float lx = rdot4(sM[0],  sM[1],  sM[2],  sM[3],  pt.x, pt.y, pt.z);
            float ly = rdot4(sM[4],  sM[5],  sM[6],  sM[7],  pt.x, pt.y, pt.z);
            float lz = rdot4(sM[8],  sM[9],  sM[10], sM[11], pt.x, pt.y, pt.z);
            float z  = rdot4(sM[24], sM[25], sM[26], sM[27], lx, ly, lz);
            float px = rdot4(sM[12], sM[13], sM[14], sM[15], lx, ly, lz);
            float py = rdot4(sM[16], sM[17], sM[18], sM[19], lx, ly, lz);
            float pz = rdot4(sM[20], sM[21], sM[22], sM[23], lx, ly, lz);
            float denom = fmaxf(pz, 1e-6f);
            float x_ = px / denom;
            float y_ = py / denom;
            bool valid = (x_ > -0.5f) && (x_ < (float)W_ - 0.5f) &&
                         (y_ > -0.5f) && (y_ < (float)H_ - 0.5f) && (z > 0.0f);
            if (valid) {
                float d = fminf(fmaxf(pz, 0.0f), clip_hi);     // clip(normalizer,0,99)
                depth = d / bev_half;                           // /100
                float vi = fminf(fmaxf(pt.w, 0.0f), 255.0f);    // clip(ilu,0,255)
                iluv = log1pf(vi) / 5.545177444479562f;         // /log(256) as f32
            }
        }
        out[base0 + rr]       = depth;
        out[base0 + HW_ + rr] = iluv;
    }
}

// ---------- fallback (R3 single-kernel path, if ws too small) ----------

#define HALF_ 56
#define CELLS_ (HALF_ * W_)

__global__ __launch_bounds__(THREADS_) void k_lidar_fused(
        const float4* __restrict__ pc, const float* __restrict__ extr,
        const float* __restrict__ intr, const float* __restrict__ view,
        float* __restrict__ out, const int* __restrict__ bev_side_p) {
    __shared__ int   win[CELLS_];
    __shared__ float sV[4][4];
    __shared__ float sE2[4];
    __shared__ float sP[3][4];

    const int i    = blockIdx.x;
    const int xcd  = i & 7;
    const int s    = i >> 3;
    const int b    = xcd + 8 * (s >= 12 ? 1 : 0);
    const int c12  = s % 12;
    const int m    = b * N_ + (c12 >> 1);
    const int rlo  = (c12 & 1) * HALF_;
    const int t    = threadIdx.x;

    if (t == 0) {
        float Vi[16];
        inv4(&view[b * 16], Vi);
        for (int ii = 0; ii < 4; ++ii)
            for (int jj = 0; jj < 4; ++jj) sV[ii][jj] = Vi[ii * 4 + jj];
    } else if (t == 64) {
        float E2[4], PFC[3][4];
        cam_mats(&extr[m * 16], &intr[m * 9], E2, PFC);
        for (int jj = 0; jj < 4; ++jj) sE2[jj] = E2[jj];
        for (int ii = 0; ii < 3; ++ii)
            for (int jj = 0; jj < 4; ++jj) sP[ii][jj] = PFC[ii][jj];
    }
    for (int k = t; k < CELLS_; k += THREADS_) win[k] = -1;
    __syncthreads();

    const float4* pcb = pc + (size_t)b * P_;
    int c0 = -1, c1 = -1, c2 = -1, c3 = -1;
    for (int p = t; p < P_; p += THREADS_) {
        float4 pt = pcb[p];
        float lx = rdot(sV[0], pt.x, pt.y, pt.z);
        float ly = rdot(sV[1], pt.x, pt.y, pt.z);
        float lz = rdot(sV[2], pt.x, pt.y, pt.z);
        float px = rdot(sP[0], lx, ly, lz);
        float py = rdot(sP[1], lx, ly, lz);
        float pz = rdot(sP[2], lx, ly, lz);
        float denom = fmaxf(pz, 1e-6f);
        float x_ = px / denom;
        float y_ = py / denom;
        int ym = (int)fminf(fmaxf(y_, 0.0f), (float)(H_ - 1));
        int xm = (int)fminf(fmaxf(x_, 0.0f), (float)(W_ - 1));
        bool is_c = (xm == 0 || xm == W_ - 1) && (ym == 0 || ym == H_ - 1);
        int code = ((ym != 0) << 1) | (xm != 0);
        c0 = (is_c && code == 0) ? p : c0;
        c1 = (is_c && code == 1) ? p : c1;
        c2 = (is_c && code == 2) ? p : c2;
        c3 = (is_c && code == 3) ? p : c3;
        int rr = ym - rlo;
        if (!is_c && (unsigned)rr < (unsigned)HALF_)
            atomicMax(&win[rr * W_ + xm], p);
    }
    for (int d = 32; d; d >>= 1) {
        c0 = max(c0, __shfl_xor(c0, d));
        c1 = max(c1, __shfl_xor(c1, d));
        c2 = max(c2, __shfl_xor(c2, d));
        c3 = max(c3, __shfl_xor(c3, d));
    }
    if ((t & 63) == 0) {
        if (rlo == 0) {
            if (c0 >= 0) atomicMax(&win[0],   c0);
            if (c1 >= 0) atomicMax(&win[199], c1);
        } else {
            if (c2 >= 0) atomicMax(&win[(H_ - 1 - rlo) * W_ + 0],   c2);
            if (c3 >= 0) atomicMax(&win[(H_ - 1 - rlo) * W_ + 199], c3);
        }
    }
    __syncthreads();

    const float bev_half = (float)bev_side_p[0] * 0.5f;
    const float clip_hi  = bev_half - 1.0f;
    const int base0 = (m * 2) * HW_ + rlo * W_;
    for (int rr = t; rr < CELLS_; rr += THREADS_) {
        int w = win[rr];
        float depth = 0.0f, iluv = 0.0f;
        if (w >= 0) {
            float4 pt = pcb[w];
            float lx = rdot(sV[0], pt.x, pt.y, pt.z);
            float ly = rdot(sV[1], pt.x, pt.y, pt.z);
            float lz = rdot(sV[2], pt.x, pt.y, pt.z);
            float z  = rdot(sE2,   lx, ly, lz);
            float px = rdot(sP[0], lx, ly, lz);
            float py = rdot(sP[1], lx, ly, lz);
            float pz = rdot(sP[2], lx, ly, lz);
            float denom = fmaxf(pz, 1e-6f);
            float x_ = px / denom;
            float y_ = py / denom;
            bool valid = (x_ > -0.5f) && (x_ < (float)W_ - 0.5f) &&
                         (y_ > -0.5f) && (y_ < (float)H_ - 0.5f) && (z > 0.0f);
            if (valid) {
                float d = fminf(fmaxf(pz, 0.0f), clip_hi);
                depth = d / bev_half;
                float vi = fminf(fmaxf(pt.w, 0.0f), 255.0f);
                iluv = log1pf(vi) / 5.545177444479562f;
            }
        }
        out[base0 + rr]       = depth;
        out[base0 + HW_ + rr] = iluv;
    }
}

// ---------- launch ----------

extern "C" void kernel_launch(void* const* d_in, const int* in_sizes, int n_in,
                              void* d_out, int out_size, void* d_ws, size_t ws_size,
                              hipStream_t stream) {
    const float4* pc  = (const float4*)d_in[0];
    const float* extr = (const float*)d_in[1];
    const float* intr = (const float*)d_in[2];
    const float* view = (const float*)d_in[3];
    const int*   bev  = (const int*)d_in[4];
    float* out = (float*)d_out;

    if (ws_size >= WS_NEED) {
        unsigned short* codes = (unsigned short*)d_ws;
        k_codes<<<dim3(B_, (P_ + K1T - 1) / K1T), dim3(K1T), 0, stream>>>(
            pc, extr, intr, view, codes);
        k_scatfin<<<dim3(BSN_ * 4), dim3(THREADS_), 0, stream>>>(
            pc, codes, extr, intr, view, out, bev);
    } else {
        k_lidar_fused<<<dim3(BSN_ * 2), dim3(THREADS_), 0, stream>>>(
            pc, extr, intr, view, out, bev);
    }
}